// Round 1
// baseline (165.983 us; speedup 1.0000x reference)
//
#include <hip/hip_runtime.h>
#include <math.h>

#define THREADS 256

// ---------------- Kernel A: channel-sum + sliding-window avgpool scores ----
// fm: (8, 384, 28, 28) f32  ->  all_scores: (8, 1595) f32
__global__ __launch_bounds__(THREADS) void score_kernel(const float* __restrict__ fm,
                                                        float* __restrict__ all_scores) {
    int b = blockIdx.x;
    int tid = threadIdx.x;
    __shared__ float s[784];  // 28x28 channel-summed map

    const float* f = fm + (size_t)b * 384 * 784;
    for (int p = tid; p < 784; p += THREADS) {
        float acc = 0.0f;
        for (int c = 0; c < 384; ++c) acc += f[(size_t)c * 784 + p];
        s[p] = acc;
    }
    __syncthreads();

    for (int widx = tid; widx < 1595; widx += THREADS) {
        int g, loc;
        if (widx < 625)       { g = 0; loc = widx; }
        else if (widx < 1154) { g = 1; loc = widx - 625; }
        else                  { g = 2; loc = widx - 1154; }
        int r    = (g == 0) ? 4 : ((g == 1) ? 6 : 8);
        int side = 29 - r;  // 25, 23, 21
        int i = loc / side, j = loc % side;
        float acc = 0.0f;
        for (int a = 0; a < r; ++a)
            for (int bb = 0; bb < r; ++bb)
                acc += s[(i + a) * 28 + (j + bb)];
        all_scores[b * 1595 + widx] = acc / (float)(r * r);
    }
}

// ---------------- Kernel B: greedy IoU-NMS per (batch, group) -------------
// Matches jnp.argmax first-occurrence tie-break + inclusive(+1) box math.
__global__ __launch_bounds__(THREADS) void nms_kernel(const float* __restrict__ all_scores,
                                                      float* __restrict__ out_idx_f,
                                                      float* __restrict__ out_sc,
                                                      int* __restrict__ ws_idx) {
    const int goffA[3] = {0, 625, 1154};
    const int gnA[3]   = {625, 529, 441};
    const int sideA[3] = {25, 23, 21};
    const int rA[3]    = {4, 6, 8};
    const int nselA[3] = {2, 3, 2};
    const int colA[3]  = {0, 2, 5};

    int b = blockIdx.x, g = blockIdx.y;
    int tid = threadIdx.x;
    int n = gnA[g], side = sideA[g], r = rA[g];
    int nsel = nselA[g], goff = goffA[g], colbase = colA[g];

    __shared__ float sc[625];
    __shared__ float rv[THREADS];
    __shared__ int   ri[THREADS];

    for (int i = tid; i < n; i += THREADS) sc[i] = all_scores[b * 1595 + goff + i];
    __syncthreads();

    float ext = (float)(r * 16 + 1);   // inclusive extent; area constant per group
    float A   = ext * ext;
    float rs  = (float)(r * 16);

    for (int k = 0; k < nsel; ++k) {
        // ---- argmax (first occurrence on ties) ----
        float bv = -INFINITY; int bi = 0x7fffffff;
        for (int i = tid; i < n; i += THREADS) {
            float v = sc[i];
            if (v > bv || (v == bv && i < bi)) { bv = v; bi = i; }
        }
        rv[tid] = bv; ri[tid] = bi;
        __syncthreads();
        for (int sft = THREADS / 2; sft > 0; sft >>= 1) {
            if (tid < sft) {
                float ov = rv[tid + sft]; int oi = ri[tid + sft];
                if (ov > rv[tid] || (ov == rv[tid] && oi < ri[tid])) {
                    rv[tid] = ov; ri[tid] = oi;
                }
            }
            __syncthreads();
        }
        int   sel  = ri[0];
        float selv = rv[0];
        if (tid == 0) {
            int outp = b * 7 + colbase + k;
            out_idx_f[outp] = (float)(goff + sel);
            out_sc[outp]    = selv;
            ws_idx[outp]    = goff + sel;
        }
        // ---- suppress by IoU > 0.25 (selected self-suppresses, iou=1) ----
        int si = sel / side, sj = sel % side;
        float sx0 = si * 16.0f, sy0 = sj * 16.0f;
        float sx1 = sx0 + rs,   sy1 = sy0 + rs;
        for (int i = tid; i < n; i += THREADS) {
            int ii = i / side, jj = i % side;
            float x0 = ii * 16.0f, y0 = jj * 16.0f;
            float x1 = x0 + rs,    y1 = y0 + rs;
            float xx0 = fmaxf(x0, sx0), yy0 = fmaxf(y0, sy0);
            float xx1 = fminf(x1, sx1), yy1 = fminf(y1, sy1);
            float w = xx1 - xx0 + 1.0f, h = yy1 - yy0 + 1.0f;
            float inter = (w < 0.0f || h < 0.0f) ? 0.0f : w * h;
            float iou = inter / (A + A - inter);
            if (iou > 0.25f) sc[i] = -INFINITY;
        }
        __syncthreads();
    }
}

// ---------------- Kernel C: gather-crop + clamped bilinear upsample -------
// One block per (proposal, channel, out-row). Matches jax.image.resize
// 'bilinear' upsampling: sample_f = (i+0.5)*(in/out)-0.5, edge-clamped.
__global__ __launch_bounds__(THREADS) void crop_kernel(const float* __restrict__ x,
                                                       const int* __restrict__ coords,
                                                       const int* __restrict__ ws_idx,
                                                       float* __restrict__ out) {
    int blk = blockIdx.x;
    int p   = blk / (3 * 448);
    int rem = blk - p * (3 * 448);
    int ch  = rem / 448;
    int oy  = rem - ch * 448;
    int b   = p / 7, col = p - b * 7;
    int g   = (col < 2) ? 0 : ((col < 5) ? 1 : 2);
    int w   = (g == 0) ? 64 : ((g == 1) ? 96 : 128);

    int gi = ws_idx[p];
    int c0 = coords[gi * 4 + 0];
    int c1 = coords[gi * 4 + 1];

    float scale = (float)w / 448.0f;
    float sy = ((float)oy + 0.5f) * scale - 0.5f;
    sy = fminf(fmaxf(sy, 0.0f), (float)(w - 1));
    int   y0 = (int)sy;             // sy >= 0, trunc == floor
    int   y1 = min(y0 + 1, w - 1);
    float ty = sy - (float)y0;

    const float* base = x + (((size_t)b * 3 + ch) * 448) * 448;
    const float* row0 = base + (size_t)(c0 + y0) * 448 + c1;
    const float* row1 = base + (size_t)(c0 + y1) * 448 + c1;
    float* orow = out + (((size_t)p * 3 + ch) * 448 + oy) * 448;

    for (int ox = threadIdx.x; ox < 448; ox += THREADS) {
        float sx = ((float)ox + 0.5f) * scale - 0.5f;
        sx = fminf(fmaxf(sx, 0.0f), (float)(w - 1));
        int   x0i = (int)sx;
        int   x1i = min(x0i + 1, w - 1);
        float tx  = sx - (float)x0i;
        float v00 = row0[x0i], v01 = row0[x1i];
        float v10 = row1[x0i], v11 = row1[x1i];
        float top = (1.0f - tx) * v00 + tx * v01;
        float bot = (1.0f - tx) * v10 + tx * v11;
        orow[ox] = (1.0f - ty) * top + ty * bot;
    }
}

// ---------------- Kernel D: logits = emb @ W + b  (8x2048 @ 2048x200) -----
__global__ __launch_bounds__(THREADS) void logits_kernel(const float* __restrict__ emb,
                                                         const float* __restrict__ W,
                                                         const float* __restrict__ bias,
                                                         float* __restrict__ out) {
    __shared__ float partial[4][64];
    int b     = blockIdx.x;
    int jbase = blockIdx.y * 64;
    int lane  = threadIdx.x & 63;
    int wave  = threadIdx.x >> 6;
    int j     = jbase + lane;
    float acc = 0.0f;
    if (j < 200) {
        const float* e = emb + (size_t)b * 2048;
        for (int k = wave * 512; k < wave * 512 + 512; ++k)
            acc += e[k] * W[(size_t)k * 200 + j];
    }
    partial[wave][lane] = acc;
    __syncthreads();
    if (wave == 0 && j < 200) {
        float s = partial[0][lane] + partial[1][lane] + partial[2][lane] + partial[3][lane];
        out[b * 200 + j] = s + bias[j];
    }
}

extern "C" void kernel_launch(void* const* d_in, const int* in_sizes, int n_in,
                              void* d_out, int out_size, void* d_ws, size_t ws_size,
                              hipStream_t stream) {
    const float* x      = (const float*)d_in[0];   // (8,3,448,448)
    const float* fm     = (const float*)d_in[1];   // (8,384,28,28)
    const float* emb    = (const float*)d_in[2];   // (8,2048)
    const float* Wc     = (const float*)d_in[3];   // (2048,200)
    const float* bc     = (const float*)d_in[4];   // (200,)
    const int*   coords = (const int*)d_in[5];     // (1595,4)

    float* out        = (float*)d_out;
    float* out_idx    = out;                  // 56  (indices, stored as float)
    float* out_sc     = out + 56;             // 56
    float* all_scores = out + 112;            // 12760
    float* imgs       = out + 12872;          // 33718272
    float* logits     = out + 33731144;       // 1600

    int* ws_idx = (int*)d_ws;                 // 56 ints of scratch

    score_kernel<<<8, THREADS, 0, stream>>>(fm, all_scores);
    nms_kernel<<<dim3(8, 3), THREADS, 0, stream>>>(all_scores, out_idx, out_sc, ws_idx);
    crop_kernel<<<56 * 3 * 448, THREADS, 0, stream>>>(x, coords, ws_idx, imgs);
    logits_kernel<<<dim3(8, 4), THREADS, 0, stream>>>(emb, Wc, bc, logits);
}

// Round 2
// 121.314 us; speedup vs baseline: 1.3682x; 1.3682x over previous
//
#include <hip/hip_runtime.h>
#include <math.h>

#define THREADS 256

// ---------------- Kernel A1: partial channel sums ------------------------
// fm: (8, 384, 28, 28) f32. Grid (8, K); each block sums 384/K channels of
// one batch into a float4 partial map (196 float4 = 784 floats).
__global__ __launch_bounds__(THREADS) void chansum_kernel(const float* __restrict__ fm,
                                                          float4* __restrict__ part,
                                                          int cpc) {
    int b = blockIdx.x, k = blockIdx.y, K = gridDim.y;
    int t = threadIdx.x;
    if (t >= 196) return;
    const float4* f = (const float4*)(fm + ((size_t)b * 384 + (size_t)k * cpc) * 784);
    float4 acc = {0.0f, 0.0f, 0.0f, 0.0f};
    for (int c = 0; c < cpc; ++c) {
        float4 v = f[(size_t)c * 196 + t];
        acc.x += v.x; acc.y += v.y; acc.z += v.z; acc.w += v.w;
    }
    part[((size_t)b * K + k) * 196 + t] = acc;
}

// ---------------- Kernel A2: finish sum + sliding-window scores ----------
// Row prefix sums in LDS: window sum = sum_a pref[i+a][j+r]-pref[i+a][j].
__global__ __launch_bounds__(THREADS) void window_kernel(const float4* __restrict__ part,
                                                         int K,
                                                         float* __restrict__ all_scores) {
    __shared__ float4 s4[196];
    __shared__ float  pref[28][29];
    float* s = (float*)s4;
    int b = blockIdx.x, t = threadIdx.x;

    if (t < 196) {
        float4 acc = {0.0f, 0.0f, 0.0f, 0.0f};
        for (int k = 0; k < K; ++k) {
            float4 v = part[((size_t)b * K + k) * 196 + t];
            acc.x += v.x; acc.y += v.y; acc.z += v.z; acc.w += v.w;
        }
        s4[t] = acc;
    }
    __syncthreads();
    if (t < 28) {
        float run = 0.0f;
        pref[t][0] = 0.0f;
        for (int j = 0; j < 28; ++j) {
            run += s[t * 28 + j];
            pref[t][j + 1] = run;
        }
    }
    __syncthreads();

    for (int widx = t; widx < 1595; widx += THREADS) {
        int g, loc;
        if (widx < 625)       { g = 0; loc = widx; }
        else if (widx < 1154) { g = 1; loc = widx - 625; }
        else                  { g = 2; loc = widx - 1154; }
        int r    = (g == 0) ? 4 : ((g == 1) ? 6 : 8);
        int side = 29 - r;  // 25, 23, 21
        int i = loc / side, j = loc % side;
        float acc = 0.0f;
        for (int a = 0; a < r; ++a)
            acc += pref[i + a][j + r] - pref[i + a][j];
        all_scores[b * 1595 + widx] = acc / (float)(r * r);
    }
}

// ---------------- Kernel B: greedy IoU-NMS per (batch, group) -------------
__global__ __launch_bounds__(THREADS) void nms_kernel(const float* __restrict__ all_scores,
                                                      float* __restrict__ out_idx_f,
                                                      float* __restrict__ out_sc,
                                                      int* __restrict__ ws_idx) {
    const int goffA[3] = {0, 625, 1154};
    const int gnA[3]   = {625, 529, 441};
    const int sideA[3] = {25, 23, 21};
    const int rA[3]    = {4, 6, 8};
    const int nselA[3] = {2, 3, 2};
    const int colA[3]  = {0, 2, 5};

    int b = blockIdx.x, g = blockIdx.y;
    int tid = threadIdx.x;
    int n = gnA[g], side = sideA[g], r = rA[g];
    int nsel = nselA[g], goff = goffA[g], colbase = colA[g];

    __shared__ float sc[625];
    __shared__ float rv[THREADS];
    __shared__ int   ri[THREADS];

    for (int i = tid; i < n; i += THREADS) sc[i] = all_scores[b * 1595 + goff + i];
    __syncthreads();

    float ext = (float)(r * 16 + 1);
    float A   = ext * ext;
    float rs  = (float)(r * 16);

    for (int k = 0; k < nsel; ++k) {
        float bv = -INFINITY; int bi = 0x7fffffff;
        for (int i = tid; i < n; i += THREADS) {
            float v = sc[i];
            if (v > bv || (v == bv && i < bi)) { bv = v; bi = i; }
        }
        rv[tid] = bv; ri[tid] = bi;
        __syncthreads();
        for (int sft = THREADS / 2; sft > 0; sft >>= 1) {
            if (tid < sft) {
                float ov = rv[tid + sft]; int oi = ri[tid + sft];
                if (ov > rv[tid] || (ov == rv[tid] && oi < ri[tid])) {
                    rv[tid] = ov; ri[tid] = oi;
                }
            }
            __syncthreads();
        }
        int   sel  = ri[0];
        float selv = rv[0];
        if (tid == 0) {
            int outp = b * 7 + colbase + k;
            out_idx_f[outp] = (float)(goff + sel);
            out_sc[outp]    = selv;
            ws_idx[outp]    = goff + sel;
        }
        int si = sel / side, sj = sel % side;
        float sx0 = si * 16.0f, sy0 = sj * 16.0f;
        float sx1 = sx0 + rs,   sy1 = sy0 + rs;
        for (int i = tid; i < n; i += THREADS) {
            int ii = i / side, jj = i % side;
            float x0 = ii * 16.0f, y0 = jj * 16.0f;
            float x1 = x0 + rs,    y1 = y0 + rs;
            float xx0 = fmaxf(x0, sx0), yy0 = fmaxf(y0, sy0);
            float xx1 = fminf(x1, sx1), yy1 = fminf(y1, sy1);
            float w = xx1 - xx0 + 1.0f, h = yy1 - yy0 + 1.0f;
            float inter = (w < 0.0f || h < 0.0f) ? 0.0f : w * h;
            float iou = inter / (A + A - inter);
            if (iou > 0.25f) sc[i] = -INFINITY;
        }
        __syncthreads();
    }
}

// ---------------- Kernel C: gather-crop + clamped bilinear upsample -------
__global__ __launch_bounds__(THREADS) void crop_kernel(const float* __restrict__ x,
                                                       const int* __restrict__ coords,
                                                       const int* __restrict__ ws_idx,
                                                       float* __restrict__ out) {
    int blk = blockIdx.x;
    int p   = blk / (3 * 448);
    int rem = blk - p * (3 * 448);
    int ch  = rem / 448;
    int oy  = rem - ch * 448;
    int b   = p / 7, col = p - b * 7;
    int g   = (col < 2) ? 0 : ((col < 5) ? 1 : 2);
    int w   = (g == 0) ? 64 : ((g == 1) ? 96 : 128);

    int gi = ws_idx[p];
    int c0 = coords[gi * 4 + 0];
    int c1 = coords[gi * 4 + 1];

    float scale = (float)w / 448.0f;
    float sy = ((float)oy + 0.5f) * scale - 0.5f;
    sy = fminf(fmaxf(sy, 0.0f), (float)(w - 1));
    int   y0 = (int)sy;
    int   y1 = min(y0 + 1, w - 1);
    float ty = sy - (float)y0;

    const float* base = x + (((size_t)b * 3 + ch) * 448) * 448;
    const float* row0 = base + (size_t)(c0 + y0) * 448 + c1;
    const float* row1 = base + (size_t)(c0 + y1) * 448 + c1;
    float* orow = out + (((size_t)p * 3 + ch) * 448 + oy) * 448;

    for (int ox = threadIdx.x; ox < 448; ox += THREADS) {
        float sx = ((float)ox + 0.5f) * scale - 0.5f;
        sx = fminf(fmaxf(sx, 0.0f), (float)(w - 1));
        int   x0i = (int)sx;
        int   x1i = min(x0i + 1, w - 1);
        float tx  = sx - (float)x0i;
        float v00 = row0[x0i], v01 = row0[x1i];
        float v10 = row1[x0i], v11 = row1[x1i];
        float top = (1.0f - tx) * v00 + tx * v01;
        float bot = (1.0f - tx) * v10 + tx * v11;
        orow[ox] = (1.0f - ty) * top + ty * bot;
    }
}

// ---------------- Kernel D: logits = emb @ W + b  (8x2048 @ 2048x200) -----
__global__ __launch_bounds__(THREADS) void logits_kernel(const float* __restrict__ emb,
                                                         const float* __restrict__ W,
                                                         const float* __restrict__ bias,
                                                         float* __restrict__ out) {
    __shared__ float partial[4][64];
    int b     = blockIdx.x;
    int jbase = blockIdx.y * 64;
    int lane  = threadIdx.x & 63;
    int wave  = threadIdx.x >> 6;
    int j     = jbase + lane;
    float acc = 0.0f;
    if (j < 200) {
        const float* e = emb + (size_t)b * 2048;
        for (int k = wave * 512; k < wave * 512 + 512; ++k)
            acc += e[k] * W[(size_t)k * 200 + j];
    }
    partial[wave][lane] = acc;
    __syncthreads();
    if (wave == 0 && j < 200) {
        float s = partial[0][lane] + partial[1][lane] + partial[2][lane] + partial[3][lane];
        out[b * 200 + j] = s + bias[j];
    }
}

extern "C" void kernel_launch(void* const* d_in, const int* in_sizes, int n_in,
                              void* d_out, int out_size, void* d_ws, size_t ws_size,
                              hipStream_t stream) {
    const float* x      = (const float*)d_in[0];   // (8,3,448,448)
    const float* fm     = (const float*)d_in[1];   // (8,384,28,28)
    const float* emb    = (const float*)d_in[2];   // (8,2048)
    const float* Wc     = (const float*)d_in[3];   // (2048,200)
    const float* bc     = (const float*)d_in[4];   // (200,)
    const int*   coords = (const int*)d_in[5];     // (1595,4)

    float* out        = (float*)d_out;
    float* out_idx    = out;                  // 56  (indices, stored as float)
    float* out_sc     = out + 56;             // 56
    float* all_scores = out + 112;            // 12760
    float* imgs       = out + 12872;          // 33718272
    float* logits     = out + 33731144;       // 1600

    int*    ws_idx = (int*)d_ws;              // 56 ints of scratch
    float4* part   = (float4*)((char*)d_ws + 1024);

    // pick channel-chunk count that fits the workspace (deterministic per run)
    int K = 16;
    while (K > 1 && ws_size < 1024 + (size_t)8 * K * 784 * 4) K >>= 1;
    int cpc = 384 / K;

    chansum_kernel<<<dim3(8, K), THREADS, 0, stream>>>(fm, part, cpc);
    window_kernel<<<8, THREADS, 0, stream>>>(part, K, all_scores);
    nms_kernel<<<dim3(8, 3), THREADS, 0, stream>>>(all_scores, out_idx, out_sc, ws_idx);
    crop_kernel<<<56 * 3 * 448, THREADS, 0, stream>>>(x, coords, ws_idx, imgs);
    logits_kernel<<<dim3(8, 4), THREADS, 0, stream>>>(emb, Wc, bc, logits);
}

// Round 4
// 98.530 us; speedup vs baseline: 1.6846x; 1.2312x over previous
//
#include <hip/hip_runtime.h>
#include <math.h>

#define THREADS 256

typedef float f32x4 __attribute__((ext_vector_type(4)));

// ---------------- Kernel A1: partial channel sums ------------------------
// fm: (8, 384, 28, 28) f32. Grid (8, K); each block sums 384/K channels of
// one batch into a float4 partial map (196 float4 = 784 floats).
__global__ __launch_bounds__(THREADS) void chansum_kernel(const float* __restrict__ fm,
                                                          float4* __restrict__ part,
                                                          int cpc) {
    int b = blockIdx.x, k = blockIdx.y, K = gridDim.y;
    int t = threadIdx.x;
    if (t >= 196) return;
    const float4* f = (const float4*)(fm + ((size_t)b * 384 + (size_t)k * cpc) * 784);
    float4 acc = {0.0f, 0.0f, 0.0f, 0.0f};
    for (int c = 0; c < cpc; ++c) {
        float4 v = f[(size_t)c * 196 + t];
        acc.x += v.x; acc.y += v.y; acc.z += v.z; acc.w += v.w;
    }
    part[((size_t)b * K + k) * 196 + t] = acc;
}

// ---------------- Kernel A2+B: finish sum + window scores + fused NMS -----
// Row prefix sums in LDS; scores kept in LDS for the NMS passes.
__global__ __launch_bounds__(THREADS) void score_nms_kernel(const float4* __restrict__ part,
                                                            int K,
                                                            float* __restrict__ all_scores,
                                                            float* __restrict__ out_idx_f,
                                                            float* __restrict__ out_sc,
                                                            int* __restrict__ ws_idx) {
    __shared__ float4 s4[196];
    __shared__ float  pref[28][29];
    __shared__ float  scl[1595];
    __shared__ float  rv[THREADS];
    __shared__ int    ri[THREADS];
    float* s = (float*)s4;
    int b = blockIdx.x, t = threadIdx.x;

    if (t < 196) {
        float4 acc = {0.0f, 0.0f, 0.0f, 0.0f};
        for (int k = 0; k < K; ++k) {
            float4 v = part[((size_t)b * K + k) * 196 + t];
            acc.x += v.x; acc.y += v.y; acc.z += v.z; acc.w += v.w;
        }
        s4[t] = acc;
    }
    __syncthreads();
    if (t < 28) {
        float run = 0.0f;
        pref[t][0] = 0.0f;
        for (int j = 0; j < 28; ++j) {
            run += s[t * 28 + j];
            pref[t][j + 1] = run;
        }
    }
    __syncthreads();

    for (int widx = t; widx < 1595; widx += THREADS) {
        int g, loc;
        if (widx < 625)       { g = 0; loc = widx; }
        else if (widx < 1154) { g = 1; loc = widx - 625; }
        else                  { g = 2; loc = widx - 1154; }
        int r    = (g == 0) ? 4 : ((g == 1) ? 6 : 8);
        int side = 29 - r;  // 25, 23, 21
        int i = loc / side, j = loc % side;
        float acc = 0.0f;
        for (int a = 0; a < r; ++a)
            acc += pref[i + a][j + r] - pref[i + a][j];
        float sv = acc / (float)(r * r);
        scl[widx] = sv;
        all_scores[b * 1595 + widx] = sv;
    }
    __syncthreads();

    // ---- greedy IoU NMS, 3 groups sequentially, scores in LDS ----
    const int goffA[3] = {0, 625, 1154};
    const int gnA[3]   = {625, 529, 441};
    const int sideA[3] = {25, 23, 21};
    const int rA[3]    = {4, 6, 8};
    const int nselA[3] = {2, 3, 2};
    const int colA[3]  = {0, 2, 5};

    for (int g = 0; g < 3; ++g) {
        int n = gnA[g], side = sideA[g], r = rA[g];
        int nsel = nselA[g], goff = goffA[g], colbase = colA[g];
        float ext = (float)(r * 16 + 1);
        float A   = ext * ext;
        float rs  = (float)(r * 16);

        for (int k = 0; k < nsel; ++k) {
            float bv = -INFINITY; int bi = 0x7fffffff;
            for (int i = t; i < n; i += THREADS) {
                float v = scl[goff + i];
                if (v > bv || (v == bv && i < bi)) { bv = v; bi = i; }
            }
            rv[t] = bv; ri[t] = bi;
            __syncthreads();
            for (int sft = THREADS / 2; sft > 0; sft >>= 1) {
                if (t < sft) {
                    float ov = rv[t + sft]; int oi = ri[t + sft];
                    if (ov > rv[t] || (ov == rv[t] && oi < ri[t])) {
                        rv[t] = ov; ri[t] = oi;
                    }
                }
                __syncthreads();
            }
            int   sel  = ri[0];
            float selv = rv[0];
            if (t == 0) {
                int outp = b * 7 + colbase + k;
                out_idx_f[outp] = (float)(goff + sel);
                out_sc[outp]    = selv;
                ws_idx[outp]    = goff + sel;
            }
            int si = sel / side, sj = sel % side;
            float sx0 = si * 16.0f, sy0 = sj * 16.0f;
            float sx1 = sx0 + rs,   sy1 = sy0 + rs;
            for (int i = t; i < n; i += THREADS) {
                int ii = i / side, jj = i % side;
                float x0 = ii * 16.0f, y0 = jj * 16.0f;
                float x1 = x0 + rs,    y1 = y0 + rs;
                float xx0 = fmaxf(x0, sx0), yy0 = fmaxf(y0, sy0);
                float xx1 = fminf(x1, sx1), yy1 = fminf(y1, sy1);
                float w = xx1 - xx0 + 1.0f, h = yy1 - yy0 + 1.0f;
                float inter = (w < 0.0f || h < 0.0f) ? 0.0f : w * h;
                float iou = inter / (A + A - inter);
                if (iou > 0.25f) scl[goff + i] = -INFINITY;
            }
            __syncthreads();
        }
    }
}

// ---------------- Kernel C: gather-crop + clamped bilinear upsample -------
// 448 threads = 4 rows x 112 col4-strips; each thread emits one float4.
// 4 consecutive outputs span <=2 source x-indices (4*scale <= 8/7), so
// 6 clamped loads + cndmask selects replace 16 gathers.
__global__ __launch_bounds__(448) void crop_kernel(const float* __restrict__ x,
                                                   const int* __restrict__ coords,
                                                   const int* __restrict__ ws_idx,
                                                   float* __restrict__ out) {
    int blk = blockIdx.x;              // p*336 + ch*112 + rg
    int p   = blk / 336;
    int rem = blk - p * 336;
    int ch  = rem / 112;
    int rg  = rem - ch * 112;
    int t   = threadIdx.x;
    int row_sub = t / 112;             // 0..3
    int col4    = t - row_sub * 112;   // 0..111
    int oy  = rg * 4 + row_sub;
    int ox0 = col4 * 4;

    int b = p / 7, col = p - b * 7;
    int g = (col < 2) ? 0 : ((col < 5) ? 1 : 2);
    int w = (g == 0) ? 64 : ((g == 1) ? 96 : 128);
    float scale = (float)w * (1.0f / 448.0f);
    float wm1   = (float)(w - 1);

    int gi = ws_idx[p];
    int c0 = coords[gi * 4 + 0];
    int c1 = coords[gi * 4 + 1];

    float sy = ((float)oy + 0.5f) * scale - 0.5f;
    sy = fminf(fmaxf(sy, 0.0f), wm1);
    int   y0 = (int)sy;
    int   y1 = min(y0 + 1, w - 1);
    float ty = sy - (float)y0;

    const float* base = x + (((size_t)b * 3 + ch) * 448) * 448;
    const float* row0 = base + (size_t)(c0 + y0) * 448 + c1;
    const float* row1 = base + (size_t)(c0 + y1) * 448 + c1;

    int   x0k[4];
    float txk[4];
    float sxb = ((float)ox0 + 0.5f) * scale - 0.5f;
    #pragma unroll
    for (int k = 0; k < 4; ++k) {
        float sx = sxb + (float)k * scale;
        sx = fminf(fmaxf(sx, 0.0f), wm1);
        int xi = (int)sx;
        x0k[k] = xi;
        txk[k] = sx - (float)xi;
    }
    int i0 = x0k[0];
    int i1 = min(i0 + 1, w - 1);
    int i2 = min(i0 + 2, w - 1);
    float a0 = row0[i0], a1 = row0[i1], a2 = row0[i2];
    float b0 = row1[i0], b1 = row1[i1], b2 = row1[i2];

    f32x4 res;
    #pragma unroll
    for (int k = 0; k < 4; ++k) {
        bool  d   = (x0k[k] != i0);
        float v00 = d ? a1 : a0;
        float v01 = d ? a2 : a1;
        float v10 = d ? b1 : b0;
        float v11 = d ? b2 : b1;
        float tx  = txk[k];
        float top = v00 + tx * (v01 - v00);
        float bot = v10 + tx * (v11 - v10);
        res[k] = top + ty * (bot - top);
    }

    float* orow = out + (((size_t)p * 3 + ch) * 448 + oy) * 448;
    __builtin_nontemporal_store(res, (f32x4*)(orow + ox0));
}

// ---------------- Kernel D: logits = emb @ W + b  (8x2048 @ 2048x200) -----
__global__ __launch_bounds__(THREADS) void logits_kernel(const float* __restrict__ emb,
                                                         const float* __restrict__ W,
                                                         const float* __restrict__ bias,
                                                         float* __restrict__ out) {
    __shared__ float partial[4][64];
    int b     = blockIdx.x;
    int jbase = blockIdx.y * 64;
    int lane  = threadIdx.x & 63;
    int wave  = threadIdx.x >> 6;
    int j     = jbase + lane;
    float acc = 0.0f;
    if (j < 200) {
        const float* e = emb + (size_t)b * 2048;
        for (int k = wave * 512; k < wave * 512 + 512; ++k)
            acc += e[k] * W[(size_t)k * 200 + j];
    }
    partial[wave][lane] = acc;
    __syncthreads();
    if (wave == 0 && j < 200) {
        float s = partial[0][lane] + partial[1][lane] + partial[2][lane] + partial[3][lane];
        out[b * 200 + j] = s + bias[j];
    }
}

extern "C" void kernel_launch(void* const* d_in, const int* in_sizes, int n_in,
                              void* d_out, int out_size, void* d_ws, size_t ws_size,
                              hipStream_t stream) {
    const float* x      = (const float*)d_in[0];   // (8,3,448,448)
    const float* fm     = (const float*)d_in[1];   // (8,384,28,28)
    const float* emb    = (const float*)d_in[2];   // (8,2048)
    const float* Wc     = (const float*)d_in[3];   // (2048,200)
    const float* bc     = (const float*)d_in[4];   // (200,)
    const int*   coords = (const int*)d_in[5];     // (1595,4)

    float* out        = (float*)d_out;
    float* out_idx    = out;                  // 56  (indices, stored as float)
    float* out_sc     = out + 56;             // 56
    float* all_scores = out + 112;            // 12760
    float* imgs       = out + 12872;          // 33718272
    float* logits     = out + 33731144;       // 1600

    int*    ws_idx = (int*)d_ws;              // 56 ints of scratch
    float4* part   = (float4*)((char*)d_ws + 1024);

    // pick channel-chunk count that fits the workspace (deterministic per run)
    int K = 16;
    while (K > 1 && ws_size < 1024 + (size_t)8 * K * 784 * 4) K >>= 1;
    int cpc = 384 / K;

    chansum_kernel<<<dim3(8, K), THREADS, 0, stream>>>(fm, part, cpc);
    score_nms_kernel<<<8, THREADS, 0, stream>>>(part, K, all_scores, out_idx, out_sc, ws_idx);
    crop_kernel<<<56 * 336, 448, 0, stream>>>(x, coords, ws_idx, imgs);
    logits_kernel<<<dim3(8, 4), THREADS, 0, stream>>>(emb, Wc, bc, logits);
}

// Round 5
// 98.367 us; speedup vs baseline: 1.6874x; 1.0017x over previous
//
#include <hip/hip_runtime.h>
#include <math.h>

#define THREADS 256

typedef float f32x4 __attribute__((ext_vector_type(4)));

// ---------------- Kernel A1: partial channel sums ------------------------
__global__ __launch_bounds__(THREADS) void chansum_kernel(const float* __restrict__ fm,
                                                          float4* __restrict__ part,
                                                          int cpc) {
    int b = blockIdx.x, k = blockIdx.y, K = gridDim.y;
    int t = threadIdx.x;
    if (t >= 196) return;
    const float4* f = (const float4*)(fm + ((size_t)b * 384 + (size_t)k * cpc) * 784);
    float4 acc = {0.0f, 0.0f, 0.0f, 0.0f};
    for (int c = 0; c < cpc; ++c) {
        float4 v = f[(size_t)c * 196 + t];
        acc.x += v.x; acc.y += v.y; acc.z += v.z; acc.w += v.w;
    }
    part[((size_t)b * K + k) * 196 + t] = acc;
}

// ---------------- Kernel A2+B: finish sum + window scores + fused NMS -----
__global__ __launch_bounds__(THREADS) void score_nms_kernel(const float4* __restrict__ part,
                                                            int K,
                                                            float* __restrict__ all_scores,
                                                            float* __restrict__ out_idx_f,
                                                            float* __restrict__ out_sc,
                                                            int* __restrict__ ws_idx) {
    __shared__ float4 s4[196];
    __shared__ float  pref[28][29];
    __shared__ float  scl[1595];
    __shared__ float  rv[8];
    __shared__ int    ri[8];
    float* s = (float*)s4;
    int b = blockIdx.x, t = threadIdx.x;

    if (t < 196) {
        float4 acc = {0.0f, 0.0f, 0.0f, 0.0f};
        for (int k = 0; k < K; ++k) {
            float4 v = part[((size_t)b * K + k) * 196 + t];
            acc.x += v.x; acc.y += v.y; acc.z += v.z; acc.w += v.w;
        }
        s4[t] = acc;
    }
    __syncthreads();
    if (t < 28) {
        float run = 0.0f;
        pref[t][0] = 0.0f;
        for (int j = 0; j < 28; ++j) {
            run += s[t * 28 + j];
            pref[t][j + 1] = run;
        }
    }
    __syncthreads();

    for (int widx = t; widx < 1595; widx += THREADS) {
        int g, loc;
        if (widx < 625)       { g = 0; loc = widx; }
        else if (widx < 1154) { g = 1; loc = widx - 625; }
        else                  { g = 2; loc = widx - 1154; }
        int r    = (g == 0) ? 4 : ((g == 1) ? 6 : 8);
        int side = 29 - r;  // 25, 23, 21
        int i = loc / side, j = loc % side;
        float acc = 0.0f;
        for (int a = 0; a < r; ++a)
            acc += pref[i + a][j + r] - pref[i + a][j];
        float sv = acc / (float)(r * r);
        scl[widx] = sv;
        all_scores[b * 1595 + widx] = sv;
    }
    __syncthreads();

    const int goffA[3] = {0, 625, 1154};
    const int gnA[3]   = {625, 529, 441};
    const int sideA[3] = {25, 23, 21};
    const int rA[3]    = {4, 6, 8};
    const int nselA[3] = {2, 3, 2};
    const int colA[3]  = {0, 2, 5};

    for (int g = 0; g < 3; ++g) {
        int n = gnA[g], side = sideA[g], r = rA[g];
        int nsel = nselA[g], goff = goffA[g], colbase = colA[g];
        float ext = (float)(r * 16 + 1);
        float A   = ext * ext;
        float rs  = (float)(r * 16);

        for (int k = 0; k < nsel; ++k) {
            // ---- argmax (smallest index among maxima == first occurrence) ----
            float bv = -INFINITY; int bi = 0x7fffffff;
            for (int i = t; i < n; i += THREADS) {
                float v = scl[goff + i];
                if (v > bv || (v == bv && i < bi)) { bv = v; bi = i; }
            }
            #pragma unroll
            for (int m = 1; m < 64; m <<= 1) {
                float ov = __shfl_xor(bv, m, 64);
                int   oi = __shfl_xor(bi, m, 64);
                if (ov > bv || (ov == bv && oi < bi)) { bv = ov; bi = oi; }
            }
            int wv = t >> 6;
            if ((t & 63) == 0) { rv[wv] = bv; ri[wv] = bi; }
            __syncthreads();
            if (t == 0) {
                for (int q = 1; q < 4; ++q) {
                    float ov = rv[q]; int oi = ri[q];
                    if (ov > bv || (ov == bv && oi < bi)) { bv = ov; bi = oi; }
                }
                rv[0] = bv; ri[0] = bi;
                int outp = b * 7 + colbase + k;
                out_idx_f[outp] = (float)(goff + bi);
                out_sc[outp]    = bv;
                ws_idx[outp]    = goff + bi;
            }
            __syncthreads();
            int sel = ri[0];
            int si = sel / side, sj = sel % side;
            float sx0 = si * 16.0f, sy0 = sj * 16.0f;
            float sx1 = sx0 + rs,   sy1 = sy0 + rs;
            for (int i = t; i < n; i += THREADS) {
                int ii = i / side, jj = i % side;
                float x0 = ii * 16.0f, y0 = jj * 16.0f;
                float x1 = x0 + rs,    y1 = y0 + rs;
                float xx0 = fmaxf(x0, sx0), yy0 = fmaxf(y0, sy0);
                float xx1 = fminf(x1, sx1), yy1 = fminf(y1, sy1);
                float w = xx1 - xx0 + 1.0f, h = yy1 - yy0 + 1.0f;
                float inter = (w < 0.0f || h < 0.0f) ? 0.0f : w * h;
                float iou = inter / (A + A - inter);
                if (iou > 0.25f) scl[goff + i] = -INFINITY;
            }
            __syncthreads();
        }
    }
}

// ---------------- Kernel C: LDS-staged crop + bilinear upsample ----------
// Block = (proposal, channel, 8-output-row stripe); 448 threads.
// Stage 4 input rows x 132 cols (edge-clamped) in LDS, then each thread
// produces 8 consecutive outputs of one row (2 f32x4 nontemporal stores).
// Bounds: 7*scale <= 2.0 keeps all taps in rows r_lo..r_lo+3; the 132-wide
// clamped fill makes l[x0+1] always valid (tx=0 at the clamp).
__global__ __launch_bounds__(448) void crop_kernel(const float* __restrict__ x,
                                                   const int* __restrict__ coords,
                                                   const int* __restrict__ ws_idx,
                                                   float* __restrict__ out) {
    __shared__ float lds[4 * 132];
    int blk = blockIdx.x;              // p*168 + ch*56 + stripe
    int p   = blk / 168;
    int rem = blk - p * 168;
    int ch  = rem / 56;
    int stripe = rem - ch * 56;
    int t = threadIdx.x;

    int b = p / 7, col = p - b * 7;
    int g = (col < 2) ? 0 : ((col < 5) ? 1 : 2);
    int w = (g == 0) ? 64 : ((g == 1) ? 96 : 128);
    float scale = (float)w * (1.0f / 448.0f);
    float wm1   = (float)(w - 1);

    int gi = ws_idx[p];
    int c0 = coords[gi * 4 + 0];
    int c1 = coords[gi * 4 + 1];

    int oy_base = stripe * 8;
    float syb = fminf(fmaxf(((float)oy_base + 0.5f) * scale - 0.5f, 0.0f), wm1);
    int r_lo = (int)syb;

    const float* base = x + (((size_t)b * 3 + ch) * 448) * 448 + c1;
    for (int i = t; i < 4 * 132; i += 448) {
        int rr = i / 132, xx = i - rr * 132;
        int yr = min(r_lo + rr, w - 1);
        int xr = min(xx, w - 1);
        lds[rr * 132 + xx] = base[(size_t)(c0 + yr) * 448 + xr];
    }
    __syncthreads();

    int row_sub = t / 56;              // 0..7
    int seg     = t - row_sub * 56;    // 0..55
    int oy  = oy_base + row_sub;
    int ox0 = seg * 8;

    float sy = fminf(fmaxf(((float)oy + 0.5f) * scale - 0.5f, 0.0f), wm1);
    int   y0 = (int)sy;
    int   y1 = min(y0 + 1, w - 1);
    float ty = sy - (float)y0;
    const float* l0 = lds + (y0 - r_lo) * 132;
    const float* l1 = lds + (y1 - r_lo) * 132;

    f32x4 res0, res1;
    #pragma unroll
    for (int k = 0; k < 8; ++k) {
        float sx = fminf(fmaxf(((float)(ox0 + k) + 0.5f) * scale - 0.5f, 0.0f), wm1);
        int   x0 = (int)sx;
        float tx = sx - (float)x0;
        float v00 = l0[x0], v01 = l0[x0 + 1];
        float v10 = l1[x0], v11 = l1[x0 + 1];
        float top = v00 + tx * (v01 - v00);
        float bot = v10 + tx * (v11 - v10);
        float r   = top + ty * (bot - top);
        if (k < 4) res0[k] = r; else res1[k - 4] = r;
    }
    float* orow = out + (((size_t)p * 3 + ch) * 448 + oy) * 448 + ox0;
    __builtin_nontemporal_store(res0, (f32x4*)orow);
    __builtin_nontemporal_store(res1, (f32x4*)(orow + 4));
}

// ---------------- Kernel D: logits = emb @ W + b  (8x2048 @ 2048x200) -----
__global__ __launch_bounds__(THREADS) void logits_kernel(const float* __restrict__ emb,
                                                         const float* __restrict__ W,
                                                         const float* __restrict__ bias,
                                                         float* __restrict__ out) {
    __shared__ float partial[4][64];
    int b     = blockIdx.x;
    int jbase = blockIdx.y * 64;
    int lane  = threadIdx.x & 63;
    int wave  = threadIdx.x >> 6;
    int j     = jbase + lane;
    float acc = 0.0f;
    if (j < 200) {
        const float* e = emb + (size_t)b * 2048;
        for (int k = wave * 512; k < wave * 512 + 512; ++k)
            acc += e[k] * W[(size_t)k * 200 + j];
    }
    partial[wave][lane] = acc;
    __syncthreads();
    if (wave == 0 && j < 200) {
        float s = partial[0][lane] + partial[1][lane] + partial[2][lane] + partial[3][lane];
        out[b * 200 + j] = s + bias[j];
    }
}

extern "C" void kernel_launch(void* const* d_in, const int* in_sizes, int n_in,
                              void* d_out, int out_size, void* d_ws, size_t ws_size,
                              hipStream_t stream) {
    const float* x      = (const float*)d_in[0];   // (8,3,448,448)
    const float* fm     = (const float*)d_in[1];   // (8,384,28,28)
    const float* emb    = (const float*)d_in[2];   // (8,2048)
    const float* Wc     = (const float*)d_in[3];   // (2048,200)
    const float* bc     = (const float*)d_in[4];   // (200,)
    const int*   coords = (const int*)d_in[5];     // (1595,4)

    float* out        = (float*)d_out;
    float* out_idx    = out;                  // 56  (indices, stored as float)
    float* out_sc     = out + 56;             // 56
    float* all_scores = out + 112;            // 12760
    float* imgs       = out + 12872;          // 33718272
    float* logits     = out + 33731144;       // 1600

    int*    ws_idx = (int*)d_ws;              // 56 ints of scratch
    float4* part   = (float4*)((char*)d_ws + 1024);

    int K = 16;
    while (K > 1 && ws_size < 1024 + (size_t)8 * K * 784 * 4) K >>= 1;
    int cpc = 384 / K;

    chansum_kernel<<<dim3(8, K), THREADS, 0, stream>>>(fm, part, cpc);
    score_nms_kernel<<<8, THREADS, 0, stream>>>(part, K, all_scores, out_idx, out_sc, ws_idx);
    crop_kernel<<<56 * 168, 448, 0, stream>>>(x, coords, ws_idx, imgs);
    logits_kernel<<<dim3(8, 4), THREADS, 0, stream>>>(emb, Wc, bc, logits);
}

// Round 6
// 65.925 us; speedup vs baseline: 2.5178x; 1.4921x over previous
//
#include <hip/hip_runtime.h>
#include <math.h>

#define THREADS 256

typedef float f32x4 __attribute__((ext_vector_type(4)));

// ---------------- Kernel A1: partial channel sums ------------------------
__global__ __launch_bounds__(THREADS) void chansum_kernel(const float* __restrict__ fm,
                                                          float4* __restrict__ part,
                                                          int cpc) {
    int b = blockIdx.x, k = blockIdx.y, K = gridDim.y;
    int t = threadIdx.x;
    if (t >= 196) return;
    const float4* f = (const float4*)(fm + ((size_t)b * 384 + (size_t)k * cpc) * 784);
    float4 acc = {0.0f, 0.0f, 0.0f, 0.0f};
    for (int c = 0; c < cpc; ++c) {
        float4 v = f[(size_t)c * 196 + t];
        acc.x += v.x; acc.y += v.y; acc.z += v.z; acc.w += v.w;
    }
    part[((size_t)b * K + k) * 196 + t] = acc;
}

// ---------------- Kernel A2+B: per-(batch,group) scores + NMS -------------
// Grid (8,3): each block finishes the channel sum + row prefix (redundant,
// cheap) then scores and NMS ONLY its group. Same float ops in same order
// per group as the fused version => bit-identical selections.
__global__ __launch_bounds__(THREADS) void score_nms_kernel(const float4* __restrict__ part,
                                                            int K,
                                                            float* __restrict__ all_scores,
                                                            float* __restrict__ out_idx_f,
                                                            float* __restrict__ out_sc,
                                                            int* __restrict__ ws_idx) {
    __shared__ float4 s4[196];
    __shared__ float  pref[28][29];
    __shared__ float  scl[625];
    __shared__ float  rv[4];
    __shared__ int    ri[4];
    float* s = (float*)s4;
    int b = blockIdx.x, g = blockIdx.y, t = threadIdx.x;

    if (t < 196) {
        float4 acc = {0.0f, 0.0f, 0.0f, 0.0f};
        for (int k = 0; k < K; ++k) {
            float4 v = part[((size_t)b * K + k) * 196 + t];
            acc.x += v.x; acc.y += v.y; acc.z += v.z; acc.w += v.w;
        }
        s4[t] = acc;
    }
    __syncthreads();
    if (t < 28) {
        float run = 0.0f;
        pref[t][0] = 0.0f;
        for (int j = 0; j < 28; ++j) {
            run += s[t * 28 + j];
            pref[t][j + 1] = run;
        }
    }
    __syncthreads();

    const int goffA[3] = {0, 625, 1154};
    const int gnA[3]   = {625, 529, 441};
    const int sideA[3] = {25, 23, 21};
    const int rA[3]    = {4, 6, 8};
    const int nselA[3] = {2, 3, 2};
    const int colA[3]  = {0, 2, 5};

    int n = gnA[g], side = sideA[g], r = rA[g];
    int nsel = nselA[g], goff = goffA[g], colbase = colA[g];
    float inv = 1.0f / (float)(r * r);

    for (int loc = t; loc < n; loc += THREADS) {
        int i = loc / side, j = loc % side;
        float acc = 0.0f;
        for (int a = 0; a < r; ++a)
            acc += pref[i + a][j + r] - pref[i + a][j];
        float sv = acc * inv;
        scl[loc] = sv;
        all_scores[b * 1595 + goff + loc] = sv;
    }
    __syncthreads();

    float ext = (float)(r * 16 + 1);
    float A   = ext * ext;
    float rs  = (float)(r * 16);

    for (int k = 0; k < nsel; ++k) {
        // argmax: (max value, min index) — first-occurrence tie-break
        float bv = -INFINITY; int bi = 0x7fffffff;
        for (int i = t; i < n; i += THREADS) {
            float v = scl[i];
            if (v > bv || (v == bv && i < bi)) { bv = v; bi = i; }
        }
        #pragma unroll
        for (int m = 1; m < 64; m <<= 1) {
            float ov = __shfl_xor(bv, m, 64);
            int   oi = __shfl_xor(bi, m, 64);
            if (ov > bv || (ov == bv && oi < bi)) { bv = ov; bi = oi; }
        }
        int wv = t >> 6;
        if ((t & 63) == 0) { rv[wv] = bv; ri[wv] = bi; }
        __syncthreads();
        if (t == 0) {
            for (int q = 1; q < 4; ++q) {
                float ov = rv[q]; int oi = ri[q];
                if (ov > bv || (ov == bv && oi < bi)) { bv = ov; bi = oi; }
            }
            ri[0] = bi;
            int outp = b * 7 + colbase + k;
            out_idx_f[outp] = (float)(goff + bi);
            out_sc[outp]    = bv;
            ws_idx[outp]    = goff + bi;
        }
        __syncthreads();
        int sel = ri[0];
        int si = sel / side, sj = sel % side;
        float sx0 = si * 16.0f, sy0 = sj * 16.0f;
        float sx1 = sx0 + rs,   sy1 = sy0 + rs;
        for (int i = t; i < n; i += THREADS) {
            int ii = i / side, jj = i % side;
            float x0 = ii * 16.0f, y0 = jj * 16.0f;
            float x1 = x0 + rs,    y1 = y0 + rs;
            float xx0 = fmaxf(x0, sx0), yy0 = fmaxf(y0, sy0);
            float xx1 = fminf(x1, sx1), yy1 = fminf(y1, sy1);
            float w = xx1 - xx0 + 1.0f, h = yy1 - yy0 + 1.0f;
            float inter = (w < 0.0f || h < 0.0f) ? 0.0f : w * h;
            float iou = inter / (A + A - inter);
            if (iou > 0.25f) scl[i] = -INFINITY;
        }
        __syncthreads();
    }
}

// ---------------- Kernel C: LDS-staged crop + bilinear upsample ----------
__global__ __launch_bounds__(448) void crop_kernel(const float* __restrict__ x,
                                                   const int* __restrict__ coords,
                                                   const int* __restrict__ ws_idx,
                                                   float* __restrict__ out) {
    __shared__ float lds[4 * 132];
    int blk = blockIdx.x;              // p*168 + ch*56 + stripe
    int p   = blk / 168;
    int rem = blk - p * 168;
    int ch  = rem / 56;
    int stripe = rem - ch * 56;
    int t = threadIdx.x;

    int b = p / 7, col = p - b * 7;
    int g = (col < 2) ? 0 : ((col < 5) ? 1 : 2);
    int w = (g == 0) ? 64 : ((g == 1) ? 96 : 128);
    float scale = (float)w * (1.0f / 448.0f);
    float wm1   = (float)(w - 1);

    int gi = ws_idx[p];
    int c0 = coords[gi * 4 + 0];
    int c1 = coords[gi * 4 + 1];

    int oy_base = stripe * 8;
    float syb = fminf(fmaxf(((float)oy_base + 0.5f) * scale - 0.5f, 0.0f), wm1);
    int r_lo = (int)syb;

    const float* base = x + (((size_t)b * 3 + ch) * 448) * 448 + c1;
    for (int i = t; i < 4 * 132; i += 448) {
        int rr = i / 132, xx = i - rr * 132;
        int yr = min(r_lo + rr, w - 1);
        int xr = min(xx, w - 1);
        lds[rr * 132 + xx] = base[(size_t)(c0 + yr) * 448 + xr];
    }
    __syncthreads();

    int row_sub = t / 56;              // 0..7
    int seg     = t - row_sub * 56;    // 0..55
    int oy  = oy_base + row_sub;
    int ox0 = seg * 8;

    float sy = fminf(fmaxf(((float)oy + 0.5f) * scale - 0.5f, 0.0f), wm1);
    int   y0 = (int)sy;
    int   y1 = min(y0 + 1, w - 1);
    float ty = sy - (float)y0;
    const float* l0 = lds + (y0 - r_lo) * 132;
    const float* l1 = lds + (y1 - r_lo) * 132;

    f32x4 res0, res1;
    #pragma unroll
    for (int k = 0; k < 8; ++k) {
        float sx = fminf(fmaxf(((float)(ox0 + k) + 0.5f) * scale - 0.5f, 0.0f), wm1);
        int   x0 = (int)sx;
        float tx = sx - (float)x0;
        float v00 = l0[x0], v01 = l0[x0 + 1];
        float v10 = l1[x0], v11 = l1[x0 + 1];
        float top = v00 + tx * (v01 - v00);
        float bot = v10 + tx * (v11 - v10);
        float r   = top + ty * (bot - top);
        if (k < 4) res0[k] = r; else res1[k - 4] = r;
    }
    float* orow = out + (((size_t)p * 3 + ch) * 448 + oy) * 448 + ox0;
    __builtin_nontemporal_store(res0, (f32x4*)orow);
    __builtin_nontemporal_store(res1, (f32x4*)(orow + 4));
}

// ---------------- Kernel D1: logits partials (k-split, coalesced W) ------
// Grid (8,16): block (b,kc) covers k in [kc*128, kc*128+128) for all 200 j.
__global__ __launch_bounds__(THREADS) void logits1_kernel(const float* __restrict__ emb,
                                                          const float* __restrict__ W,
                                                          float* __restrict__ lpart) {
    int b = blockIdx.x, kc = blockIdx.y;
    int t = threadIdx.x;
    if (t >= 200) return;
    const float* e = emb + (size_t)b * 2048 + kc * 128;
    const float* wp = W + (size_t)kc * 128 * 200 + t;
    float acc = 0.0f;
    #pragma unroll 4
    for (int k = 0; k < 128; ++k)
        acc += e[k] * wp[(size_t)k * 200];
    lpart[((size_t)b * 16 + kc) * 200 + t] = acc;
}

// ---------------- Kernel D2: reduce partials + bias ----------------------
__global__ __launch_bounds__(THREADS) void logits2_kernel(const float* __restrict__ lpart,
                                                          const float* __restrict__ bias,
                                                          float* __restrict__ out) {
    int b = blockIdx.x, t = threadIdx.x;
    if (t >= 200) return;
    float acc = bias[t];
    #pragma unroll
    for (int kc = 0; kc < 16; ++kc)
        acc += lpart[((size_t)b * 16 + kc) * 200 + t];
    out[b * 200 + t] = acc;
}

extern "C" void kernel_launch(void* const* d_in, const int* in_sizes, int n_in,
                              void* d_out, int out_size, void* d_ws, size_t ws_size,
                              hipStream_t stream) {
    const float* x      = (const float*)d_in[0];   // (8,3,448,448)
    const float* fm     = (const float*)d_in[1];   // (8,384,28,28)
    const float* emb    = (const float*)d_in[2];   // (8,2048)
    const float* Wc     = (const float*)d_in[3];   // (2048,200)
    const float* bc     = (const float*)d_in[4];   // (200,)
    const int*   coords = (const int*)d_in[5];     // (1595,4)

    float* out        = (float*)d_out;
    float* out_idx    = out;                  // 56  (indices, stored as float)
    float* out_sc     = out + 56;             // 56
    float* all_scores = out + 112;            // 12760
    float* imgs       = out + 12872;          // 33718272
    float* logits     = out + 33731144;       // 1600

    int*    ws_idx = (int*)d_ws;                               // 56 ints
    float4* part   = (float4*)((char*)d_ws + 1024);            // 8*16*784 f
    float*  lpart  = (float*)((char*)d_ws + 1024 + 8 * 16 * 784 * 4); // 25600 f

    int K = 16;
    while (K > 1 && ws_size < 1024 + (size_t)8 * 16 * 784 * 4 + 25600 * 4) K >>= 1;
    int cpc = 384 / K;

    chansum_kernel<<<dim3(8, K), THREADS, 0, stream>>>(fm, part, cpc);
    logits1_kernel<<<dim3(8, 16), THREADS, 0, stream>>>(emb, Wc, lpart);
    score_nms_kernel<<<dim3(8, 3), THREADS, 0, stream>>>(part, K, all_scores, out_idx, out_sc, ws_idx);
    crop_kernel<<<56 * 168, 448, 0, stream>>>(x, coords, ws_idx, imgs);
    logits2_kernel<<<8, THREADS, 0, stream>>>(lpart, bc, logits);
}

// Round 7
// 61.301 us; speedup vs baseline: 2.7077x; 1.0754x over previous
//
#include <hip/hip_runtime.h>
#include <math.h>

#define THREADS 256

typedef float f32x4 __attribute__((ext_vector_type(4)));

// ---------------- Launch 1: chansum (8*K blocks) + logits1 (128 blocks) ---
// chansum: block (b,k) sums cpc channels of batch b into float4 partials.
// logits1: block (b,kc) covers k in [kc*128, kc*128+128) for all 200 cols.
__global__ __launch_bounds__(THREADS) void fused1_kernel(const float* __restrict__ fm,
                                                         float4* __restrict__ part,
                                                         int cpc, int K,
                                                         const float* __restrict__ emb,
                                                         const float* __restrict__ W,
                                                         float* __restrict__ lpart) {
    int blk = blockIdx.x;
    int t = threadIdx.x;
    if (blk < 8 * K) {
        int b = blk / K, k = blk - b * K;
        if (t >= 196) return;
        const float4* f = (const float4*)(fm + ((size_t)b * 384 + (size_t)k * cpc) * 784);
        float4 acc = {0.0f, 0.0f, 0.0f, 0.0f};
        for (int c = 0; c < cpc; ++c) {
            float4 v = f[(size_t)c * 196 + t];
            acc.x += v.x; acc.y += v.y; acc.z += v.z; acc.w += v.w;
        }
        part[((size_t)b * K + k) * 196 + t] = acc;
    } else {
        int idx = blk - 8 * K;
        int b = idx >> 4, kc = idx & 15;
        if (t >= 200) return;
        const float* e  = emb + (size_t)b * 2048 + kc * 128;
        const float* wp = W + (size_t)kc * 128 * 200 + t;
        float acc = 0.0f;
        #pragma unroll 4
        for (int k = 0; k < 128; ++k)
            acc += e[k] * wp[(size_t)k * 200];
        lpart[((size_t)b * 16 + kc) * 200 + t] = acc;
    }
}

// ---------------- Launch 2: score+NMS (24 blocks) + logits2 (1 block) -----
// Per (batch,group): finish channel sum, row prefix, window scores, greedy
// IoU NMS. Same float ops in same order per group => stable selections.
__global__ __launch_bounds__(THREADS) void fused2_kernel(const float4* __restrict__ part,
                                                         int K,
                                                         float* __restrict__ all_scores,
                                                         float* __restrict__ out_idx_f,
                                                         float* __restrict__ out_sc,
                                                         int* __restrict__ ws_idx,
                                                         const float* __restrict__ lpart,
                                                         const float* __restrict__ bias,
                                                         float* __restrict__ logits) {
    __shared__ float4 s4[196];
    __shared__ float  pref[28][29];
    __shared__ float  scl[625];
    __shared__ float  rv[4];
    __shared__ int    ri[4];
    int t = threadIdx.x;

    if (blockIdx.x == 24) {          // logits2: reduce partials + bias
        if (t >= 200) return;
        for (int b = 0; b < 8; ++b) {
            float acc = bias[t];
            #pragma unroll
            for (int kc = 0; kc < 16; ++kc)
                acc += lpart[((size_t)b * 16 + kc) * 200 + t];
            logits[b * 200 + t] = acc;
        }
        return;
    }

    float* s = (float*)s4;
    int b = blockIdx.x / 3, g = blockIdx.x - b * 3;

    if (t < 196) {
        float4 acc = {0.0f, 0.0f, 0.0f, 0.0f};
        for (int k = 0; k < K; ++k) {
            float4 v = part[((size_t)b * K + k) * 196 + t];
            acc.x += v.x; acc.y += v.y; acc.z += v.z; acc.w += v.w;
        }
        s4[t] = acc;
    }
    __syncthreads();
    if (t < 28) {
        float run = 0.0f;
        pref[t][0] = 0.0f;
        for (int j = 0; j < 28; ++j) {
            run += s[t * 28 + j];
            pref[t][j + 1] = run;
        }
    }
    __syncthreads();

    const int goffA[3] = {0, 625, 1154};
    const int gnA[3]   = {625, 529, 441};
    const int sideA[3] = {25, 23, 21};
    const int rA[3]    = {4, 6, 8};
    const int nselA[3] = {2, 3, 2};
    const int colA[3]  = {0, 2, 5};

    int n = gnA[g], side = sideA[g], r = rA[g];
    int nsel = nselA[g], goff = goffA[g], colbase = colA[g];
    float inv = 1.0f / (float)(r * r);

    for (int loc = t; loc < n; loc += THREADS) {
        int i = loc / side, j = loc % side;
        float acc = 0.0f;
        for (int a = 0; a < r; ++a)
            acc += pref[i + a][j + r] - pref[i + a][j];
        float sv = acc * inv;
        scl[loc] = sv;
        all_scores[b * 1595 + goff + loc] = sv;
    }
    __syncthreads();

    float ext = (float)(r * 16 + 1);
    float A   = ext * ext;
    float rs  = (float)(r * 16);

    for (int k = 0; k < nsel; ++k) {
        // argmax: (max value, min index) — first-occurrence tie-break
        float bv = -INFINITY; int bi = 0x7fffffff;
        for (int i = t; i < n; i += THREADS) {
            float v = scl[i];
            if (v > bv || (v == bv && i < bi)) { bv = v; bi = i; }
        }
        #pragma unroll
        for (int m = 1; m < 64; m <<= 1) {
            float ov = __shfl_xor(bv, m, 64);
            int   oi = __shfl_xor(bi, m, 64);
            if (ov > bv || (ov == bv && oi < bi)) { bv = ov; bi = oi; }
        }
        int wv = t >> 6;
        if ((t & 63) == 0) { rv[wv] = bv; ri[wv] = bi; }
        __syncthreads();
        if (t == 0) {
            for (int q = 1; q < 4; ++q) {
                float ov = rv[q]; int oi = ri[q];
                if (ov > bv || (ov == bv && oi < bi)) { bv = ov; bi = oi; }
            }
            ri[0] = bi;
            int outp = b * 7 + colbase + k;
            out_idx_f[outp] = (float)(goff + bi);
            out_sc[outp]    = bv;
            ws_idx[outp]    = goff + bi;
        }
        __syncthreads();
        int sel = ri[0];
        int si = sel / side, sj = sel % side;
        float sx0 = si * 16.0f, sy0 = sj * 16.0f;
        float sx1 = sx0 + rs,   sy1 = sy0 + rs;
        for (int i = t; i < n; i += THREADS) {
            int ii = i / side, jj = i % side;
            float x0 = ii * 16.0f, y0 = jj * 16.0f;
            float x1 = x0 + rs,    y1 = y0 + rs;
            float xx0 = fmaxf(x0, sx0), yy0 = fmaxf(y0, sy0);
            float xx1 = fminf(x1, sx1), yy1 = fminf(y1, sy1);
            float w = xx1 - xx0 + 1.0f, h = yy1 - yy0 + 1.0f;
            float inter = (w < 0.0f || h < 0.0f) ? 0.0f : w * h;
            float iou = inter / (A + A - inter);
            if (iou > 0.25f) scl[i] = -INFINITY;
        }
        __syncthreads();
    }
}

// ---------------- Launch 3: LDS-staged crop + bilinear upsample ----------
// Block = (proposal, channel, 8-output-row stripe); 448 threads.
// Stage 4 input rows x 132 cols (edge-clamped) in LDS; each thread emits
// 8 consecutive outputs of one row via two PLAIN f32x4 stores (the harness
// fill kernel proves plain stores sustain ~6.7 TB/s).
__global__ __launch_bounds__(448) void crop_kernel(const float* __restrict__ x,
                                                   const int* __restrict__ coords,
                                                   const int* __restrict__ ws_idx,
                                                   float* __restrict__ out) {
    __shared__ float lds[4 * 132];
    int blk = blockIdx.x;              // p*168 + ch*56 + stripe
    int p   = blk / 168;
    int rem = blk - p * 168;
    int ch  = rem / 56;
    int stripe = rem - ch * 56;
    int t = threadIdx.x;

    int b = p / 7, col = p - b * 7;
    int g = (col < 2) ? 0 : ((col < 5) ? 1 : 2);
    int w = (g == 0) ? 64 : ((g == 1) ? 96 : 128);
    float scale = (float)w * (1.0f / 448.0f);
    float wm1   = (float)(w - 1);

    int gi = ws_idx[p];
    int c0 = coords[gi * 4 + 0];
    int c1 = coords[gi * 4 + 1];

    int oy_base = stripe * 8;
    float syb = fminf(fmaxf(((float)oy_base + 0.5f) * scale - 0.5f, 0.0f), wm1);
    int r_lo = (int)syb;

    const float* base = x + (((size_t)b * 3 + ch) * 448) * 448 + c1;
    for (int i = t; i < 4 * 132; i += 448) {
        int rr = i / 132, xx = i - rr * 132;
        int yr = min(r_lo + rr, w - 1);
        int xr = min(xx, w - 1);
        lds[rr * 132 + xx] = base[(size_t)(c0 + yr) * 448 + xr];
    }
    __syncthreads();

    int row_sub = t / 56;              // 0..7
    int seg     = t - row_sub * 56;    // 0..55
    int oy  = oy_base + row_sub;
    int ox0 = seg * 8;

    float sy = fminf(fmaxf(((float)oy + 0.5f) * scale - 0.5f, 0.0f), wm1);
    int   y0 = (int)sy;
    int   y1 = min(y0 + 1, w - 1);
    float ty = sy - (float)y0;
    const float* l0 = lds + (y0 - r_lo) * 132;
    const float* l1 = lds + (y1 - r_lo) * 132;

    f32x4 res0, res1;
    #pragma unroll
    for (int k = 0; k < 8; ++k) {
        float sx = fminf(fmaxf(((float)(ox0 + k) + 0.5f) * scale - 0.5f, 0.0f), wm1);
        int   x0 = (int)sx;
        float tx = sx - (float)x0;
        float v00 = l0[x0], v01 = l0[x0 + 1];
        float v10 = l1[x0], v11 = l1[x0 + 1];
        float top = v00 + tx * (v01 - v00);
        float bot = v10 + tx * (v11 - v10);
        float r   = top + ty * (bot - top);
        if (k < 4) res0[k] = r; else res1[k - 4] = r;
    }
    float* orow = out + (((size_t)p * 3 + ch) * 448 + oy) * 448 + ox0;
    *(f32x4*)orow       = res0;
    *(f32x4*)(orow + 4) = res1;
}

extern "C" void kernel_launch(void* const* d_in, const int* in_sizes, int n_in,
                              void* d_out, int out_size, void* d_ws, size_t ws_size,
                              hipStream_t stream) {
    const float* x      = (const float*)d_in[0];   // (8,3,448,448)
    const float* fm     = (const float*)d_in[1];   // (8,384,28,28)
    const float* emb    = (const float*)d_in[2];   // (8,2048)
    const float* Wc     = (const float*)d_in[3];   // (2048,200)
    const float* bc     = (const float*)d_in[4];   // (200,)
    const int*   coords = (const int*)d_in[5];     // (1595,4)

    float* out        = (float*)d_out;
    float* out_idx    = out;                  // 56  (indices, stored as float)
    float* out_sc     = out + 56;             // 56
    float* all_scores = out + 112;            // 12760
    float* imgs       = out + 12872;          // 33718272
    float* logits     = out + 33731144;       // 1600

    int K = 32;
    while (K > 1 && ws_size < 1024 + (size_t)8 * K * 784 * 4 + 25600 * 4) K >>= 1;
    int cpc = 384 / K;

    int*    ws_idx = (int*)d_ws;                                   // 56 ints
    float4* part   = (float4*)((char*)d_ws + 1024);                // 8*K*196 float4
    float*  lpart  = (float*)((char*)d_ws + 1024 + (size_t)8 * K * 784 * 4);

    fused1_kernel<<<8 * K + 128, THREADS, 0, stream>>>(fm, part, cpc, K, emb, Wc, lpart);
    fused2_kernel<<<25, THREADS, 0, stream>>>(part, K, all_scores, out_idx, out_sc, ws_idx,
                                              lpart, bc, logits);
    crop_kernel<<<56 * 168, 448, 0, stream>>>(x, coords, ws_idx, imgs);
}

// Round 8
// 59.580 us; speedup vs baseline: 2.7859x; 1.0289x over previous
//
#include <hip/hip_runtime.h>
#include <math.h>

#define THREADS 256

typedef float f32x4 __attribute__((ext_vector_type(4)));

// ---------------- Launch 1: chansum (8*K blocks) + logits1 (128 blocks) ---
__global__ __launch_bounds__(THREADS) void fused1_kernel(const float* __restrict__ fm,
                                                         float4* __restrict__ part,
                                                         int cpc, int K,
                                                         const float* __restrict__ emb,
                                                         const float* __restrict__ W,
                                                         float* __restrict__ lpart) {
    int blk = blockIdx.x;
    int t = threadIdx.x;
    if (blk < 8 * K) {
        int b = blk / K, k = blk - b * K;
        if (t >= 196) return;
        const float4* f = (const float4*)(fm + ((size_t)b * 384 + (size_t)k * cpc) * 784);
        float4 acc = {0.0f, 0.0f, 0.0f, 0.0f};
        for (int c = 0; c < cpc; ++c) {
            float4 v = f[(size_t)c * 196 + t];
            acc.x += v.x; acc.y += v.y; acc.z += v.z; acc.w += v.w;
        }
        part[((size_t)b * K + k) * 196 + t] = acc;
    } else {
        int idx = blk - 8 * K;
        int b = idx >> 4, kc = idx & 15;
        if (t >= 200) return;
        const float* e  = emb + (size_t)b * 2048 + kc * 128;
        const float* wp = W + (size_t)kc * 128 * 200 + t;
        float acc = 0.0f;
        #pragma unroll 4
        for (int k = 0; k < 128; ++k)
            acc += e[k] * wp[(size_t)k * 200];
        lpart[((size_t)b * 16 + kc) * 200 + t] = acc;
    }
}

// ---------------- Launch 2: score+NMS (24 blocks) + logits2 (8 blocks) ----
__global__ __launch_bounds__(THREADS) void fused2_kernel(const float4* __restrict__ part,
                                                         int K,
                                                         float* __restrict__ all_scores,
                                                         float* __restrict__ out_idx_f,
                                                         float* __restrict__ out_sc,
                                                         int* __restrict__ ws_idx,
                                                         const float* __restrict__ lpart,
                                                         const float* __restrict__ bias,
                                                         float* __restrict__ logits) {
    __shared__ float4 s4[196];
    __shared__ float  pref[28][29];
    __shared__ float  scl[625];
    __shared__ float  rv[4];
    __shared__ int    ri[4];
    int t = threadIdx.x;

    if (blockIdx.x >= 24) {          // logits2: reduce partials + bias, 1 block/batch
        int b = blockIdx.x - 24;
        if (t >= 200) return;
        float acc = bias[t];
        #pragma unroll
        for (int kc = 0; kc < 16; ++kc)
            acc += lpart[((size_t)b * 16 + kc) * 200 + t];
        logits[b * 200 + t] = acc;
        return;
    }

    float* s = (float*)s4;
    int b = blockIdx.x / 3, g = blockIdx.x - b * 3;

    if (t < 196) {
        float4 acc = {0.0f, 0.0f, 0.0f, 0.0f};
        for (int k = 0; k < K; ++k) {
            float4 v = part[((size_t)b * K + k) * 196 + t];
            acc.x += v.x; acc.y += v.y; acc.z += v.z; acc.w += v.w;
        }
        s4[t] = acc;
    }
    __syncthreads();
    if (t < 28) {
        float run = 0.0f;
        pref[t][0] = 0.0f;
        for (int j = 0; j < 28; ++j) {
            run += s[t * 28 + j];
            pref[t][j + 1] = run;
        }
    }
    __syncthreads();

    const int goffA[3] = {0, 625, 1154};
    const int gnA[3]   = {625, 529, 441};
    const int sideA[3] = {25, 23, 21};
    const int rA[3]    = {4, 6, 8};
    const int nselA[3] = {2, 3, 2};
    const int colA[3]  = {0, 2, 5};

    int n = gnA[g], side = sideA[g], r = rA[g];
    int nsel = nselA[g], goff = goffA[g], colbase = colA[g];
    float inv = 1.0f / (float)(r * r);

    for (int loc = t; loc < n; loc += THREADS) {
        int i = loc / side, j = loc % side;
        float acc = 0.0f;
        for (int a = 0; a < r; ++a)
            acc += pref[i + a][j + r] - pref[i + a][j];
        float sv = acc * inv;
        scl[loc] = sv;
        all_scores[b * 1595 + goff + loc] = sv;
    }
    __syncthreads();

    float ext = (float)(r * 16 + 1);
    float A   = ext * ext;
    float rs  = (float)(r * 16);

    for (int k = 0; k < nsel; ++k) {
        float bv = -INFINITY; int bi = 0x7fffffff;
        for (int i = t; i < n; i += THREADS) {
            float v = scl[i];
            if (v > bv || (v == bv && i < bi)) { bv = v; bi = i; }
        }
        #pragma unroll
        for (int m = 1; m < 64; m <<= 1) {
            float ov = __shfl_xor(bv, m, 64);
            int   oi = __shfl_xor(bi, m, 64);
            if (ov > bv || (ov == bv && oi < bi)) { bv = ov; bi = oi; }
        }
        int wv = t >> 6;
        if ((t & 63) == 0) { rv[wv] = bv; ri[wv] = bi; }
        __syncthreads();
        if (t == 0) {
            for (int q = 1; q < 4; ++q) {
                float ov = rv[q]; int oi = ri[q];
                if (ov > bv || (ov == bv && oi < bi)) { bv = ov; bi = oi; }
            }
            ri[0] = bi;
            int outp = b * 7 + colbase + k;
            out_idx_f[outp] = (float)(goff + bi);
            out_sc[outp]    = bv;
            ws_idx[outp]    = goff + bi;
        }
        __syncthreads();
        int sel = ri[0];
        int si = sel / side, sj = sel % side;
        float sx0 = si * 16.0f, sy0 = sj * 16.0f;
        float sx1 = sx0 + rs,   sy1 = sy0 + rs;
        for (int i = t; i < n; i += THREADS) {
            int ii = i / side, jj = i % side;
            float x0 = ii * 16.0f, y0 = jj * 16.0f;
            float x1 = x0 + rs,    y1 = y0 + rs;
            float xx0 = fmaxf(x0, sx0), yy0 = fmaxf(y0, sy0);
            float xx1 = fminf(x1, sx1), yy1 = fminf(y1, sy1);
            float w = xx1 - xx0 + 1.0f, h = yy1 - yy0 + 1.0f;
            float inter = (w < 0.0f || h < 0.0f) ? 0.0f : w * h;
            float iou = inter / (A + A - inter);
            if (iou > 0.25f) scl[i] = -INFINITY;
        }
        __syncthreads();
    }
}

// ---------------- Launch 3: crop + bilinear, register-staged taps ---------
// Block = (proposal, channel, 16-output-row stripe); 448 threads.
// Stage 7 input rows x 132 cols (covers 15*scale<=4.29 span +y1) in LDS.
// Each thread: one 8-col segment on two output rows. Since 8 outputs span
// <=2.29 source px, x0(k)-x0(0) in {0,1,2}: load 4 consecutive floats/row
// ONCE (8 ds_read total for 16 outputs) and produce outputs via selects.
__global__ __launch_bounds__(448) void crop_kernel(const float* __restrict__ x,
                                                   const int* __restrict__ coords,
                                                   const int* __restrict__ ws_idx,
                                                   float* __restrict__ out) {
    __shared__ float lds[7 * 132];
    int blk = blockIdx.x;              // p*84 + ch*28 + stripe
    int p   = blk / 84;
    int rem = blk - p * 84;
    int ch  = rem / 28;
    int stripe = rem - ch * 28;
    int t = threadIdx.x;

    int b = p / 7, col = p - b * 7;
    int g = (col < 2) ? 0 : ((col < 5) ? 1 : 2);
    int w = (g == 0) ? 64 : ((g == 1) ? 96 : 128);
    float scale = (float)w * (1.0f / 448.0f);
    float wm1   = (float)(w - 1);

    int gi = ws_idx[p];
    int c0 = coords[gi * 4 + 0];
    int c1 = coords[gi * 4 + 1];

    int S = stripe * 16;
    float syb = fminf(fmaxf(((float)S + 0.5f) * scale - 0.5f, 0.0f), wm1);
    int r_lo = (int)syb;

    const float* base = x + (((size_t)b * 3 + ch) * 448) * 448 + c1;
    for (int i = t; i < 7 * 132; i += 448) {
        int rr = i / 132, xx = i - rr * 132;
        lds[i] = base[(size_t)(c0 + min(r_lo + rr, w - 1)) * 448 + min(xx, w - 1)];
    }
    __syncthreads();

    int row_sub = t / 56;              // 0..7
    int seg     = t - row_sub * 56;    // 0..55
    int ox0 = seg * 8;

    // x-geometry shared by both output rows
    float sxb = ((float)ox0 + 0.5f) * scale - 0.5f;
    float sx0 = fminf(fmaxf(sxb, 0.0f), wm1);
    int   i0  = (int)sx0;
    int   dk[8];
    float txk[8];
    #pragma unroll
    for (int k = 0; k < 8; ++k) {
        float sx = fminf(fmaxf(sxb + (float)k * scale, 0.0f), wm1);
        int xi = (int)sx;
        dk[k]  = xi - i0;              // 0, 1, or 2
        txk[k] = sx - (float)xi;
    }

    #pragma unroll
    for (int half = 0; half < 2; ++half) {
        int oy = S + half * 8 + row_sub;
        float sy = fminf(fmaxf(((float)oy + 0.5f) * scale - 0.5f, 0.0f), wm1);
        int   y0 = (int)sy;
        int   y1 = min(y0 + 1, w - 1);
        float ty = sy - (float)y0;
        const float* l0 = lds + (y0 - r_lo) * 132 + i0;
        const float* l1 = lds + (y1 - r_lo) * 132 + i0;
        float a0 = l0[0], a1 = l0[1], a2 = l0[2], a3 = l0[3];
        float b0 = l1[0], b1 = l1[1], b2 = l1[2], b3 = l1[3];

        f32x4 res0, res1;
        #pragma unroll
        for (int k = 0; k < 8; ++k) {
            int   d   = dk[k];
            float v00 = (d == 0) ? a0 : ((d == 1) ? a1 : a2);
            float v01 = (d == 0) ? a1 : ((d == 1) ? a2 : a3);
            float v10 = (d == 0) ? b0 : ((d == 1) ? b1 : b2);
            float v11 = (d == 0) ? b1 : ((d == 1) ? b2 : b3);
            float tx  = txk[k];
            float top = v00 + tx * (v01 - v00);
            float bot = v10 + tx * (v11 - v10);
            float r   = top + ty * (bot - top);
            if (k < 4) res0[k] = r; else res1[k - 4] = r;
        }
        float* orow = out + (((size_t)p * 3 + ch) * 448 + oy) * 448 + ox0;
        *(f32x4*)orow       = res0;
        *(f32x4*)(orow + 4) = res1;
    }
}

extern "C" void kernel_launch(void* const* d_in, const int* in_sizes, int n_in,
                              void* d_out, int out_size, void* d_ws, size_t ws_size,
                              hipStream_t stream) {
    const float* x      = (const float*)d_in[0];   // (8,3,448,448)
    const float* fm     = (const float*)d_in[1];   // (8,384,28,28)
    const float* emb    = (const float*)d_in[2];   // (8,2048)
    const float* Wc     = (const float*)d_in[3];   // (2048,200)
    const float* bc     = (const float*)d_in[4];   // (200,)
    const int*   coords = (const int*)d_in[5];     // (1595,4)

    float* out        = (float*)d_out;
    float* out_idx    = out;                  // 56  (indices, stored as float)
    float* out_sc     = out + 56;             // 56
    float* all_scores = out + 112;            // 12760
    float* imgs       = out + 12872;          // 33718272
    float* logits     = out + 33731144;       // 1600

    int K = 32;
    while (K > 1 && ws_size < 1024 + (size_t)8 * K * 784 * 4 + 25600 * 4) K >>= 1;
    int cpc = 384 / K;

    int*    ws_idx = (int*)d_ws;                                   // 56 ints
    float4* part   = (float4*)((char*)d_ws + 1024);                // 8*K*196 float4
    float*  lpart  = (float*)((char*)d_ws + 1024 + (size_t)8 * K * 784 * 4);

    fused1_kernel<<<8 * K + 128, THREADS, 0, stream>>>(fm, part, cpc, K, emb, Wc, lpart);
    fused2_kernel<<<32, THREADS, 0, stream>>>(part, K, all_scores, out_idx, out_sc, ws_idx,
                                              lpart, bc, logits);
    crop_kernel<<<56 * 84, 448, 0, stream>>>(x, coords, ws_idx, imgs);
}

// Round 9
// 53.124 us; speedup vs baseline: 3.1245x; 1.1215x over previous
//
#include <hip/hip_runtime.h>
#include <math.h>

#define THREADS 256

typedef float f32x4 __attribute__((ext_vector_type(4)));

// ---------------- Launch 1: chansum (8*K blocks) + logits1 (128 blocks) ---
__global__ __launch_bounds__(THREADS) void fused1_kernel(const float* __restrict__ fm,
                                                         float4* __restrict__ part,
                                                         int cpc, int K,
                                                         const float* __restrict__ emb,
                                                         const float* __restrict__ W,
                                                         float* __restrict__ lpart) {
    int blk = blockIdx.x;
    int t = threadIdx.x;
    if (blk < 8 * K) {
        int b = blk / K, k = blk - b * K;
        if (t >= 196) return;
        const float4* f = (const float4*)(fm + ((size_t)b * 384 + (size_t)k * cpc) * 784);
        float4 acc = {0.0f, 0.0f, 0.0f, 0.0f};
        for (int c = 0; c < cpc; ++c) {
            float4 v = f[(size_t)c * 196 + t];
            acc.x += v.x; acc.y += v.y; acc.z += v.z; acc.w += v.w;
        }
        part[((size_t)b * K + k) * 196 + t] = acc;
    } else {
        int idx = blk - 8 * K;
        int b = idx >> 4, kc = idx & 15;
        if (t >= 200) return;
        const float* e  = emb + (size_t)b * 2048 + kc * 128;
        const float* wp = W + (size_t)kc * 128 * 200 + t;
        float acc = 0.0f;
        #pragma unroll 4
        for (int k = 0; k < 128; ++k)
            acc += e[k] * wp[(size_t)k * 200];
        lpart[((size_t)b * 16 + kc) * 200 + t] = acc;
    }
}

// ---------------- Launch 2: score+NMS (24 blocks) + logits2 (8 blocks) ----
__global__ __launch_bounds__(THREADS) void fused2_kernel(const float4* __restrict__ part,
                                                         int K,
                                                         float* __restrict__ all_scores,
                                                         float* __restrict__ out_idx_f,
                                                         float* __restrict__ out_sc,
                                                         int* __restrict__ ws_idx,
                                                         const float* __restrict__ lpart,
                                                         const float* __restrict__ bias,
                                                         float* __restrict__ logits) {
    __shared__ float4 s4[196];
    __shared__ float  pref[28][29];
    __shared__ float  scl[625];
    __shared__ float  rv[4];
    __shared__ int    ri[4];
    int t = threadIdx.x;

    if (blockIdx.x >= 24) {          // logits2: reduce partials + bias, 1 block/batch
        int b = blockIdx.x - 24;
        if (t >= 200) return;
        float acc = bias[t];
        #pragma unroll
        for (int kc = 0; kc < 16; ++kc)
            acc += lpart[((size_t)b * 16 + kc) * 200 + t];
        logits[b * 200 + t] = acc;
        return;
    }

    int b = blockIdx.x / 3, g = blockIdx.x - b * 3;

    if (t < 196) {
        float4 acc = {0.0f, 0.0f, 0.0f, 0.0f};
        #pragma unroll 8
        for (int k = 0; k < K; ++k) {
            float4 v = part[((size_t)b * K + k) * 196 + t];
            acc.x += v.x; acc.y += v.y; acc.z += v.z; acc.w += v.w;
        }
        s4[t] = acc;
    }
    __syncthreads();
    if (t < 28) {
        // row prefix scan: 7 float4 LDS reads into regs, unrolled scan (no serial LDS chain)
        float4 row[7];
        #pragma unroll
        for (int i = 0; i < 7; ++i) row[i] = s4[t * 7 + i];
        float run = 0.0f;
        pref[t][0] = 0.0f;
        #pragma unroll
        for (int j = 0; j < 28; ++j) {
            run += ((float*)row)[j];
            pref[t][j + 1] = run;
        }
    }
    __syncthreads();

    const int gnA[3]   = {625, 529, 441};
    const int sideA[3] = {25, 23, 21};
    const int rA[3]    = {4, 6, 8};
    const int nselA[3] = {2, 3, 2};
    const int colA[3]  = {0, 2, 5};
    const int goffA[3] = {0, 625, 1154};

    int n = gnA[g], side = sideA[g], r = rA[g];
    int nsel = nselA[g], goff = goffA[g], colbase = colA[g];
    float inv = 1.0f / (float)(r * r);

    for (int loc = t; loc < n; loc += THREADS) {
        int i = loc / side, j = loc % side;
        float acc = 0.0f;
        for (int a = 0; a < r; ++a)
            acc += pref[i + a][j + r] - pref[i + a][j];
        float sv = acc * inv;
        scl[loc] = sv;
        all_scores[b * 1595 + goff + loc] = sv;
    }
    __syncthreads();

    float ext = (float)(r * 16 + 1);
    float A   = ext * ext;
    float rs  = (float)(r * 16);

    for (int k = 0; k < nsel; ++k) {
        float bv = -INFINITY; int bi = 0x7fffffff;
        for (int i = t; i < n; i += THREADS) {
            float v = scl[i];
            if (v > bv || (v == bv && i < bi)) { bv = v; bi = i; }
        }
        #pragma unroll
        for (int m = 1; m < 64; m <<= 1) {
            float ov = __shfl_xor(bv, m, 64);
            int   oi = __shfl_xor(bi, m, 64);
            if (ov > bv || (ov == bv && oi < bi)) { bv = ov; bi = oi; }
        }
        int wv = t >> 6;
        if ((t & 63) == 0) { rv[wv] = bv; ri[wv] = bi; }
        __syncthreads();
        if (t == 0) {
            for (int q = 1; q < 4; ++q) {
                float ov = rv[q]; int oi = ri[q];
                if (ov > bv || (ov == bv && oi < bi)) { bv = ov; bi = oi; }
            }
            ri[0] = bi;
            int outp = b * 7 + colbase + k;
            out_idx_f[outp] = (float)(goff + bi);
            out_sc[outp]    = bv;
            ws_idx[outp]    = goff + bi;
        }
        __syncthreads();
        int sel = ri[0];
        int si = sel / side, sj = sel % side;
        float sx0 = si * 16.0f, sy0 = sj * 16.0f;
        float sx1 = sx0 + rs,   sy1 = sy0 + rs;
        for (int i = t; i < n; i += THREADS) {
            int ii = i / side, jj = i % side;
            float x0 = ii * 16.0f, y0 = jj * 16.0f;
            float x1 = x0 + rs,    y1 = y0 + rs;
            float xx0 = fmaxf(x0, sx0), yy0 = fmaxf(y0, sy0);
            float xx1 = fminf(x1, sx1), yy1 = fminf(y1, sy1);
            float w = xx1 - xx0 + 1.0f, h = yy1 - yy0 + 1.0f;
            float inter = (w < 0.0f || h < 0.0f) ? 0.0f : w * h;
            float iou = inter / (A + A - inter);
            if (iou > 0.25f) scl[i] = -INFINITY;
        }
        __syncthreads();
    }
}

// ---------------- Launch 3: persistent pipelined crop ---------------------
// 1024 blocks x 448 threads; task = (p, ch, 16-row stripe), 4704 tasks,
// block walks tasks with stride gridDim. Double-buffered LDS stage (7x132
// rows/task): per task {ds_write cur; issue gloads next; barrier;
// compute+store cur} — one barrier/task, next task's HBM latency hides
// under current task's compute & stores.
#define CROP_GRID 1024
#define NTASK (56 * 3 * 28)

__global__ __launch_bounds__(448) void crop_kernel(const float* __restrict__ x,
                                                   const int* __restrict__ coords,
                                                   const int* __restrict__ ws_idx,
                                                   float* __restrict__ out) {
    __shared__ float lds[2][7 * 132];
    int t = threadIdx.x;

    // per-thread constants across tasks
    int rr0 = t / 132,        xx0 = t - rr0 * 132;          // i = t
    int i1  = t + 448;
    int rr1 = i1 / 132,       xx1 = i1 - rr1 * 132;          // i = t+448
    int rr2 = 6,              xx2 = t + 104;                 // i = t+896 (t<28)
    int row_sub = t / 56;             // 0..7
    int seg     = t - row_sub * 56;   // 0..55
    int ox0 = seg * 8;

    // ---- geometry of task -> scalars (cur/nxt sets) ----
    int task = blockIdx.x;

    // cur geometry
    int    c_w, c_rlo, c_S;
    float  c_scale, c_wm1;
    size_t c_outb;
    const float* c_base;
    float rA, rB, rC;

    {
        int p = task / 84, rem = task - p * 84;
        int ch = rem / 28, stripe = rem - ch * 28;
        int b = p / 7, col = p - b * 7;
        int g = (col < 2) ? 0 : ((col < 5) ? 1 : 2);
        c_w = (g == 0) ? 64 : ((g == 1) ? 96 : 128);
        c_scale = (float)c_w * (1.0f / 448.0f);
        c_wm1 = (float)(c_w - 1);
        c_S = stripe * 16;
        float syb = fminf(fmaxf(((float)c_S + 0.5f) * c_scale - 0.5f, 0.0f), c_wm1);
        c_rlo = (int)syb;
        int gi = ws_idx[p];
        int c0 = coords[gi * 4 + 0];
        int c1 = coords[gi * 4 + 1];
        c_base = x + (((size_t)b * 3 + ch) * 448) * 448 + c1 + (size_t)c0 * 448;
        c_outb = (((size_t)p * 3 + ch) * 448) * 448;
        rA = c_base[(size_t)min(c_rlo + rr0, c_w - 1) * 448 + min(xx0, c_w - 1)];
        rB = c_base[(size_t)min(c_rlo + rr1, c_w - 1) * 448 + min(xx1, c_w - 1)];
        if (t < 28)
            rC = c_base[(size_t)min(c_rlo + rr2, c_w - 1) * 448 + min(xx2, c_w - 1)];
    }

    int buf = 0;
    while (true) {
        // stage current task into LDS
        lds[buf][t]       = rA;
        lds[buf][t + 448] = rB;
        if (t < 28) lds[buf][t + 896] = rC;

        // issue next task's loads (hide HBM latency under compute below)
        int nxt = task + CROP_GRID;
        bool has_nxt = nxt < NTASK;
        int    n_w = 0, n_rlo = 0, n_S = 0;
        float  n_scale = 0.0f, n_wm1 = 0.0f;
        size_t n_outb = 0;
        const float* n_base = nullptr;
        float nA = 0.0f, nB = 0.0f, nC = 0.0f;
        if (has_nxt) {
            int p = nxt / 84, rem = nxt - p * 84;
            int ch = rem / 28, stripe = rem - ch * 28;
            int b = p / 7, col = p - b * 7;
            int g = (col < 2) ? 0 : ((col < 5) ? 1 : 2);
            n_w = (g == 0) ? 64 : ((g == 1) ? 96 : 128);
            n_scale = (float)n_w * (1.0f / 448.0f);
            n_wm1 = (float)(n_w - 1);
            n_S = stripe * 16;
            float syb = fminf(fmaxf(((float)n_S + 0.5f) * n_scale - 0.5f, 0.0f), n_wm1);
            n_rlo = (int)syb;
            int gi = ws_idx[p];
            int c0 = coords[gi * 4 + 0];
            int c1 = coords[gi * 4 + 1];
            n_base = x + (((size_t)b * 3 + ch) * 448) * 448 + c1 + (size_t)c0 * 448;
            n_outb = (((size_t)p * 3 + ch) * 448) * 448;
            nA = n_base[(size_t)min(n_rlo + rr0, n_w - 1) * 448 + min(xx0, n_w - 1)];
            nB = n_base[(size_t)min(n_rlo + rr1, n_w - 1) * 448 + min(xx1, n_w - 1)];
            if (t < 28)
                nC = n_base[(size_t)min(n_rlo + rr2, n_w - 1) * 448 + min(xx2, n_w - 1)];
        }

        __syncthreads();

        // ---- compute current task: 2 output rows x 8 cols per thread ----
        {
            float sxb = ((float)ox0 + 0.5f) * c_scale - 0.5f;
            float sxc = fminf(fmaxf(sxb, 0.0f), c_wm1);
            int   i0  = (int)sxc;
            int   dk[8];
            float txk[8];
            #pragma unroll
            for (int k = 0; k < 8; ++k) {
                float sx = fminf(fmaxf(sxb + (float)k * c_scale, 0.0f), c_wm1);
                int xi = (int)sx;
                dk[k]  = xi - i0;          // 0, 1, or 2
                txk[k] = sx - (float)xi;
            }
            const float* lbase = &lds[buf][0];
            #pragma unroll
            for (int half = 0; half < 2; ++half) {
                int oy = c_S + half * 8 + row_sub;
                float sy = fminf(fmaxf(((float)oy + 0.5f) * c_scale - 0.5f, 0.0f), c_wm1);
                int   y0 = (int)sy;
                int   y1 = min(y0 + 1, c_w - 1);
                float ty = sy - (float)y0;
                const float* l0 = lbase + (y0 - c_rlo) * 132 + i0;
                const float* l1 = lbase + (y1 - c_rlo) * 132 + i0;
                float a0 = l0[0], a1 = l0[1], a2 = l0[2], a3 = l0[3];
                float b0 = l1[0], b1 = l1[1], b2 = l1[2], b3 = l1[3];

                f32x4 res0, res1;
                #pragma unroll
                for (int k = 0; k < 8; ++k) {
                    int   d   = dk[k];
                    float v00 = (d == 0) ? a0 : ((d == 1) ? a1 : a2);
                    float v01 = (d == 0) ? a1 : ((d == 1) ? a2 : a3);
                    float v10 = (d == 0) ? b0 : ((d == 1) ? b1 : b2);
                    float v11 = (d == 0) ? b1 : ((d == 1) ? b2 : b3);
                    float tx  = txk[k];
                    float top = v00 + tx * (v01 - v00);
                    float bot = v10 + tx * (v11 - v10);
                    float rr  = top + ty * (bot - top);
                    if (k < 4) res0[k] = rr; else res1[k - 4] = rr;
                }
                float* orow = out + c_outb + (size_t)oy * 448 + ox0;
                *(f32x4*)orow       = res0;
                *(f32x4*)(orow + 4) = res1;
            }
        }

        if (!has_nxt) break;
        // rotate next -> cur
        c_w = n_w; c_rlo = n_rlo; c_S = n_S;
        c_scale = n_scale; c_wm1 = n_wm1;
        c_outb = n_outb; c_base = n_base;
        rA = nA; rB = nB; rC = nC;
        task = nxt;
        buf ^= 1;
    }
}

extern "C" void kernel_launch(void* const* d_in, const int* in_sizes, int n_in,
                              void* d_out, int out_size, void* d_ws, size_t ws_size,
                              hipStream_t stream) {
    const float* x      = (const float*)d_in[0];   // (8,3,448,448)
    const float* fm     = (const float*)d_in[1];   // (8,384,28,28)
    const float* emb    = (const float*)d_in[2];   // (8,2048)
    const float* Wc     = (const float*)d_in[3];   // (2048,200)
    const float* bc     = (const float*)d_in[4];   // (200,)
    const int*   coords = (const int*)d_in[5];     // (1595,4)

    float* out        = (float*)d_out;
    float* out_idx    = out;                  // 56  (indices, stored as float)
    float* out_sc     = out + 56;             // 56
    float* all_scores = out + 112;            // 12760
    float* imgs       = out + 12872;          // 33718272
    float* logits     = out + 33731144;       // 1600

    int K = 32;
    while (K > 1 && ws_size < 1024 + (size_t)8 * K * 784 * 4 + 25600 * 4) K >>= 1;
    int cpc = 384 / K;

    int*    ws_idx = (int*)d_ws;                                   // 56 ints
    float4* part   = (float4*)((char*)d_ws + 1024);                // 8*K*196 float4
    float*  lpart  = (float*)((char*)d_ws + 1024 + (size_t)8 * K * 784 * 4);

    fused1_kernel<<<8 * K + 128, THREADS, 0, stream>>>(fm, part, cpc, K, emb, Wc, lpart);
    fused2_kernel<<<32, THREADS, 0, stream>>>(part, K, all_scores, out_idx, out_sc, ws_idx,
                                              lpart, bc, logits);
    crop_kernel<<<CROP_GRID, 448, 0, stream>>>(x, coords, ws_idx, imgs);
}